// Round 6
// baseline (211.862 us; speedup 1.0000x reference)
//
#include <hip/hip_runtime.h>

// KNN k-th smallest distance, two-pass threshold-filter MFMA version.
// dist = sqrt(2 - 2*dot(zn,rn)); sorted(dist)[k] == (k+1)-th LARGEST dot.
//  1) normalize_bf16: fused z+ref rows -> L2-normalized bf16
//  2) knn_pass<1>:  MFMA dots, per-(row,chunk,lane16) subset MAX
//  3) knn_threshold: per row, exact 11th-largest of 2048 subset maxes -> T
//  4) knn_pass<2>:  MFMA dots again, keep v >= T[row] via atomic append
//  5) knn_final: exact 11th-largest of survivors -> dist
//
// Round-6 restructure: NO LDS, NO barriers.  Evidence: pass time (~44us) is
// invariant to intra-block schedule (r0/r1), L2 traffic (r3), and residency
// (r5) -> the stage->vmcnt->barrier rhythm IS the cost (m233: 2-phase
// structure ~72% overhead).  After the XCD swizzle each XCD's B-chunks are
// 1.6MB = L2-resident, so LDS sharing buys nothing (Common-mistake #7:
// staging L2-fit data is pure overhead).  New shape:
//  - wave owns 64 query rows: afr[4][4] in regs, 4x B-reuse per fragment
//  - B-fragments loaded straight from global (L2) per 16-ref col-tile:
//    4 x bf16x8 loads + 16 MFMA + 16 fmax; depth-1 manual rotation with two
//    named fragment sets (static indexing, rule #20)
//  - block = 4 independent waves = 256 query rows; grid 8 x NCH(128) = 1024
//    blocks; bijective XCD swizzle -> 16 chunks/XCD (1.6MB, L2-fit), all 8
//    row-blocks of a chunk on the same XCD
//  - no __launch_bounds__ min-waves (round-4 spill lesson); natural VGPR
//
// Accuracy: bf16 rounding perturbs each dot by ~3.5e-4; k-th order statistic
// is 1-Lipschitz in that perturbation -> << 2.39e-2 threshold.  Threshold
// bound: subsets (chunk,ln) partition the refs per row (epilogue masks
// g < c1, so no chunk overlap); a subset max > v11 implies the subset holds
// a top-10 dot -> at most 10 such subsets -> T (11th-largest subset max)
// <= v11, so all top-11 dots survive the v >= T filter.

#define D_DIM 128
#define TQB 256        // queries per block (4 waves x 64 rows)
#define NCH 128        // ref chunks; grid 8*128=1024 blocks; 1024%8==0
#define NSUB (NCH * 16) // subsets per row = 2048
#define KK 11          // selection slots (k=10 -> 11th largest)
#define CAP 256        // survivor capacity per row

typedef __bf16 bf16_t;
typedef bf16_t bf16x8 __attribute__((ext_vector_type(8)));
typedef float f32x4 __attribute__((ext_vector_type(4)));

__device__ __forceinline__ unsigned short f2bf(float f) {
    unsigned u = __float_as_uint(f);
    return (unsigned short)((u + 0x7fffu + ((u >> 16) & 1u)) >> 16);  // RNE
}

__global__ __launch_bounds__(256) void normalize_bf16(
    const float* __restrict__ z, const float* __restrict__ ref,
    unsigned short* __restrict__ zb, unsigned short* __restrict__ rb,
    int N, int M)
{
    const int w = threadIdx.x >> 6;
    const int l = threadIdx.x & 63;
    const int row = blockIdx.x * 4 + w;
    if (row >= N + M) return;
    const float* in; unsigned short* out; int r;
    if (row < N) { in = z;   out = zb; r = row; }
    else         { in = ref; out = rb; r = row - N; }
    const float2 v = ((const float2*)in)[(size_t)r * 64 + l];
    float ss = v.x * v.x + v.y * v.y;
    #pragma unroll
    for (int off = 32; off > 0; off >>= 1) ss += __shfl_xor(ss, off);
    const float inv = rsqrtf(ss);
    ushort2 o; o.x = f2bf(v.x * inv); o.y = f2bf(v.y * inv);
    ((ushort2*)out)[(size_t)r * 64 + l] = o;
}

// PASS==1: write subset maxes.  PASS==2: filter vs T, append survivors.
template <int PASS>
__global__ __launch_bounds__(256) void knn_pass(
    const unsigned short* __restrict__ zb, const unsigned short* __restrict__ rb,
    float* __restrict__ maxes, const float* __restrict__ T,
    int* __restrict__ cnt, float* __restrict__ surv,
    int N, int M, int chunk)
{
    // T1 XCD swizzle: XCD k owns chunks [16k,16k+16) exclusively (1.6MB
    // L2-fit) and ALL 8 row-blocks of each chunk (B reuse within the XCD).
    const int nwg = 8 * NCH;                              // 1024, %8==0
    const int bid = (int)blockIdx.x + 8 * (int)blockIdx.y;
    const int swz = (bid & 7) * (nwg >> 3) + (bid >> 3);
    const int bx = swz & 7;
    const int by = swz >> 3;

    const int lane = threadIdx.x & 63;
    const int w = threadIdx.x >> 6;    // wave -> rows bx*256 + w*64 ..+63
    const int quad = lane >> 4;
    const int ln = lane & 15;
    const int rbase = bx * TQB + w * 64;
    const int c0 = by * chunk;
    const int c1 = min(c0 + chunk, M);
    const int ntile = (c1 - c0 + 15) >> 4;   // 16-ref col-tiles (25 here)

    // A fragments, loop-invariant, straight from L2-resident zb.
    bf16x8 afr[4][4];
    #pragma unroll
    for (int rt = 0; rt < 4; ++rt)
        #pragma unroll
        for (int ks = 0; ks < 4; ++ks)
            afr[rt][ks] = *(const bf16x8*)
                &zb[(size_t)(rbase + rt * 16 + ln) * D_DIM + ks * 32 + quad * 8];

    float mx[4][4];   // pass1: subset max, row rt*16+quad*4+r, col-class ln
    float tr[4][4];   // pass2: per-row thresholds
    if (PASS == 1) {
        #pragma unroll
        for (int rt = 0; rt < 4; ++rt)
            #pragma unroll
            for (int r = 0; r < 4; ++r) mx[rt][r] = -3.0f;
    } else {
        #pragma unroll
        for (int rt = 0; rt < 4; ++rt)
            #pragma unroll
            for (int r = 0; r < 4; ++r)
                tr[rt][r] = T[rbase + rt * 16 + quad * 4 + r];
    }

    // Load one 16-ref col-tile's B fragments (4 x bf16x8 = 16B/lane each).
    // Lane (ln,quad) reads ref row c0+tile*16+ln, elems ks*32+quad*8 --
    // same pattern as the A loads; served by the XCD's L2.
    auto loadB = [&](bf16x8* b, int tile) {
        int g = c0 + tile * 16 + ln;
        if (g > M - 1) g = M - 1;              // addr clamp; masked below
        const unsigned short* bp = &rb[(size_t)g * D_DIM + quad * 8];
        #pragma unroll
        for (int ks = 0; ks < 4; ++ks) b[ks] = *(const bf16x8*)(bp + ks * 32);
    };

    // 16 MFMA (4 ks x 4 rt) + epilogue for one col-tile.
    auto compute = [&](const bf16x8* b, int tile) {
        f32x4 acc[4];
        #pragma unroll
        for (int rt = 0; rt < 4; ++rt) acc[rt] = (f32x4){0.f, 0.f, 0.f, 0.f};
        #pragma unroll
        for (int ks = 0; ks < 4; ++ks)
            #pragma unroll
            for (int rt = 0; rt < 4; ++rt)
                acc[rt] = __builtin_amdgcn_mfma_f32_16x16x32_bf16(
                    afr[rt][ks], b[ks], acc[rt], 0, 0, 0);
        const int g = c0 + tile * 16 + ln;
        if (g < c1) {                          // chunk mask: keeps subsets
            if (PASS == 1) {                   // a true partition of refs
                #pragma unroll
                for (int rt = 0; rt < 4; ++rt)
                    #pragma unroll
                    for (int r = 0; r < 4; ++r)
                        mx[rt][r] = fmaxf(mx[rt][r], acc[rt][r]);
            } else {
                #pragma unroll
                for (int rt = 0; rt < 4; ++rt)
                    #pragma unroll
                    for (int r = 0; r < 4; ++r) {
                        float v = acc[rt][r];
                        if (v >= tr[rt][r]) {  // rare
                            int row = rbase + rt * 16 + quad * 4 + r;
                            int slot = atomicAdd(&cnt[row], 1);
                            if (slot < CAP) surv[(size_t)row * CAP + slot] = v;
                        }
                    }
            }
        }
    };

    // Depth-1 rotated stream: load t+1 issues before compute(t)'s MFMAs
    // retire; no barriers anywhere -- waves fully independent, TLP + ILP
    // hide the ~200cyc L2 latency.
    bf16x8 ba[4], bb[4];
    loadB(ba, 0);
    if (ntile > 1) loadB(bb, 1);
    int tl = 0;
    for (;;) {
        compute(ba, tl);
        if (tl + 2 < ntile) loadB(ba, tl + 2);
        if (++tl >= ntile) break;
        compute(bb, tl);
        if (tl + 2 < ntile) loadB(bb, tl + 2);
        if (++tl >= ntile) break;
    }

    if (PASS == 1) {
        #pragma unroll
        for (int rt = 0; rt < 4; ++rt)
            #pragma unroll
            for (int r = 0; r < 4; ++r) {
                int row = rbase + rt * 16 + quad * 4 + r;
                maxes[(size_t)row * NSUB + by * 16 + ln] = mx[rt][r];
            }
    }
}

// Per-lane sorted top-(KK) slots, then kk+1 global max-extractions with
// static-shift pop (rule #20: no dynamic register indexing).
__device__ __forceinline__ float kth_largest_64(float* s, int kk, int t) {
    float cur = -3.0f;
    for (int it = 0; it <= kk; ++it) {
        float m = s[0];
        #pragma unroll
        for (int off = 32; off > 0; off >>= 1) m = fmaxf(m, __shfl_xor(m, off));
        cur = m;
        unsigned long long b = __ballot(s[0] == m);
        bool owner = ((int)(__ffsll(b) - 1) == t);
        #pragma unroll
        for (int j = 0; j < KK - 1; ++j) s[j] = owner ? s[j + 1] : s[j];
        if (owner) s[KK - 1] = -3.0f;
    }
    return cur;
}

__global__ __launch_bounds__(64) void knn_threshold(
    const float* __restrict__ maxes, const int* __restrict__ kp,
    float* __restrict__ T, int* __restrict__ cnt)
{
    const int row = blockIdx.x;
    const int t = threadIdx.x;
    float s[KK];
    #pragma unroll
    for (int j = 0; j < KK; ++j) s[j] = -3.0f;
    #pragma unroll
    for (int i = 0; i < NSUB / 64; ++i) {     // 32 coalesced loads
        float v = maxes[(size_t)row * NSUB + t + 64 * i];
        #pragma unroll
        for (int j = 0; j < KK; ++j) {        // descending sorted insert
            float hi = fmaxf(s[j], v), lo = fminf(s[j], v);
            s[j] = hi; v = lo;
        }
    }
    const int kk = *kp;   // 10
    float cur = kth_largest_64(s, kk, t);
    if (t == 0) { T[row] = cur; cnt[row] = 0; }
}

__global__ __launch_bounds__(64) void knn_final(
    const float* __restrict__ surv, const int* __restrict__ cnt,
    const int* __restrict__ kp, float* __restrict__ out)
{
    const int row = blockIdx.x;
    const int t = threadIdx.x;
    int c = cnt[row]; if (c > CAP) c = CAP;
    float s[KK];
    #pragma unroll
    for (int j = 0; j < KK; ++j) s[j] = -3.0f;
    #pragma unroll
    for (int i = 0; i < CAP / 64; ++i) {      // 4 coalesced loads
        int idx = t + 64 * i;
        float v = (idx < c) ? surv[(size_t)row * CAP + idx] : -3.0f;
        #pragma unroll
        for (int j = 0; j < KK; ++j) {
            float hi = fmaxf(s[j], v), lo = fminf(s[j], v);
            s[j] = hi; v = lo;
        }
    }
    const int kk = *kp;
    float cur = kth_largest_64(s, kk, t);
    if (t == 0) out[row] = sqrtf(fmaxf(2.0f - 2.0f * cur, 1e-12f));
}

extern "C" void kernel_launch(void* const* d_in, const int* in_sizes, int n_in,
                              void* d_out, int out_size, void* d_ws, size_t ws_size,
                              hipStream_t stream) {
    const float* z   = (const float*)d_in[0];
    const float* ref = (const float*)d_in[1];
    const int*   kp  = (const int*)d_in[2];
    float* out = (float*)d_out;

    const int N = in_sizes[0] / D_DIM;   // 2048
    const int M = in_sizes[1] / D_DIM;   // 50000

    unsigned short* zbuf = (unsigned short*)d_ws;             // N*128 bf16
    unsigned short* rbuf = zbuf + (size_t)N * D_DIM;          // M*128 bf16
    float* maxes = (float*)(rbuf + (size_t)M * D_DIM);        // N*NSUB f32 (16MB)
    float* T     = maxes + (size_t)N * NSUB;                  // N f32
    int*   cnt   = (int*)(T + N);                             // N i32
    float* surv  = (float*)(cnt + N);                         // N*CAP f32 (2MB)

    normalize_bf16<<<(N + M + 3) / 4, 256, 0, stream>>>(z, ref, zbuf, rbuf, N, M);

    const int chunk = (M + NCH - 1) / NCH;    // 391
    dim3 grid(N / TQB, NCH);                  // 8 x 128 = 1024 blocks

    knn_pass<1><<<grid, 256, 0, stream>>>(zbuf, rbuf, maxes, nullptr,
                                          nullptr, nullptr, N, M, chunk);
    knn_threshold<<<N, 64, 0, stream>>>(maxes, kp, T, cnt);
    knn_pass<2><<<grid, 256, 0, stream>>>(zbuf, rbuf, nullptr, T,
                                          cnt, surv, N, M, chunk);
    knn_final<<<N, 64, 0, stream>>>(surv, cnt, kp, out);
}

// Round 7
// 187.177 us; speedup vs baseline: 1.1319x; 1.1319x over previous
//
#include <hip/hip_runtime.h>

// KNN k-th smallest distance, two-pass threshold-filter MFMA version.
// dist = sqrt(2 - 2*dot(zn,rn)); sorted(dist)[k] == (k+1)-th LARGEST dot.
//  1) normalize_bf16: fused z+ref rows -> L2-normalized bf16
//  2) knn_pass<1>:  MFMA dots, epilogue = per-(row,chunk,lane16) subset MAX
//  3) knn_threshold: per row, exact 11th-largest of 1536 subset maxes -> T
//  4) knn_pass<2>:  MFMA dots again, keep v >= T[row] via atomic append
//  5) knn_final: exact 11th-largest of survivors -> dist
//
// Round-7 change (single variable vs round-3/5 known-good): MFMA work per
// barrier event x2.  Ledger: pass time invariant to intra-iter schedule
// (r0/r1), L2 traffic (r3), residency (r5); no-LDS streaming regressed
// (r6: L2 latency >> per-tile compute).  Per CU per pass MFMA needs 25.6k
// cyc but measured ~107k -> ~80k is the per-iteration stage/vmcnt/barrier
// rhythm (m233: structural).  Untested lever: amortization.
//  - TQ=256: wave owns 64 query rows (afr[4][4]; r6 measured VGPR 76-92 for
//    this register shape -> fits).  Per wave-iter: 64 MFMA + 16 ds_read
//    (4:1 vs 2:1), half the barrier events per unit work.
//  - B staging machinery IDENTICAL to round-3: BR=64, 32KB double-buffer,
//    gld_lds width-16, counted vmcnt(4), XOR slot swizzle via pre-swizzled
//    global source.  acc[4] live per-ct only.
//  - grid 8 x NCH(96) = 768 blocks = 3/CU; 768%8==0 bijective XCD swizzle;
//    12 chunks/XCD = 1.6MB L2-fit.  nt=9 (chunk=521).
//  - no __launch_bounds__ min-waves (round-4 spill lesson).
//
// Accuracy: bf16 rounding perturbs each dot by ~3.5e-4; k-th order statistic
// is 1-Lipschitz in that perturbation -> << 2.39e-2 threshold.  Threshold
// bound: subsets (chunk,ln) partition the refs per row (epilogue masks
// g < c1 -> no chunk overlap); a subset max > v11 implies the subset holds
// a top-10 dot -> at most 10 such subsets -> T (11th-largest subset max)
// <= v11, so all top-11 dots survive the v >= T filter.

#define D_DIM 128
#define TQB 256        // queries per block (4 waves x 64 rows)
#define BR 64          // refs per block iteration
#define NCH 96         // ref chunks; grid 8*96=768 blocks = 3/CU; 768%8==0
#define NSUB (NCH * 16) // subsets per row = 1536
#define KK 11          // selection slots (k=10 -> 11th largest)
#define CAP 256        // survivor capacity per row

typedef __bf16 bf16_t;
typedef bf16_t bf16x8 __attribute__((ext_vector_type(8)));
typedef float f32x4 __attribute__((ext_vector_type(4)));

__device__ __forceinline__ unsigned short f2bf(float f) {
    unsigned u = __float_as_uint(f);
    return (unsigned short)((u + 0x7fffu + ((u >> 16) & 1u)) >> 16);  // RNE
}

__global__ __launch_bounds__(256) void normalize_bf16(
    const float* __restrict__ z, const float* __restrict__ ref,
    unsigned short* __restrict__ zb, unsigned short* __restrict__ rb,
    int N, int M)
{
    const int w = threadIdx.x >> 6;
    const int l = threadIdx.x & 63;
    const int row = blockIdx.x * 4 + w;
    if (row >= N + M) return;
    const float* in; unsigned short* out; int r;
    if (row < N) { in = z;   out = zb; r = row; }
    else         { in = ref; out = rb; r = row - N; }
    const float2 v = ((const float2*)in)[(size_t)r * 64 + l];
    float ss = v.x * v.x + v.y * v.y;
    #pragma unroll
    for (int off = 32; off > 0; off >>= 1) ss += __shfl_xor(ss, off);
    const float inv = rsqrtf(ss);
    ushort2 o; o.x = f2bf(v.x * inv); o.y = f2bf(v.y * inv);
    ((ushort2*)out)[(size_t)r * 64 + l] = o;
}

// async global->LDS, 16B per lane; LDS dest is wave-uniform base + lane*16.
__device__ __forceinline__ void gld_lds16(const unsigned short* g,
                                          unsigned short* l) {
    __builtin_amdgcn_global_load_lds(
        (__attribute__((address_space(1))) void*)g,
        (__attribute__((address_space(3))) void*)l, 16, 0, 0);
}

// PASS==1: write subset maxes.  PASS==2: filter vs T, append survivors.
template <int PASS>
__global__ __launch_bounds__(256) void knn_pass(
    const unsigned short* __restrict__ zb, const unsigned short* __restrict__ rb,
    float* __restrict__ maxes, const float* __restrict__ T,
    int* __restrict__ cnt, float* __restrict__ surv,
    int N, int M, int chunk)
{
    // Double-buffered B tile: 2 x 64 rows x 128 bf16 (256B/row, no pad;
    // bank spread comes from the XOR slot swizzle).  32 KiB total.
    __shared__ __align__(16) unsigned short Bt[2 * BR * D_DIM];

    // T1 XCD swizzle: XCD k owns ref-chunks [12k,12k+12) exclusively (1.6MB,
    // L2-fit), and all 8 row-blocks of each chunk land on the same XCD.
    const int nwg = 8 * NCH;                              // 768, %8 == 0
    const int bid = (int)blockIdx.x + 8 * (int)blockIdx.y;
    const int swz = (bid & 7) * (nwg >> 3) + (bid >> 3);
    const int bx = swz & 7;
    const int by = swz >> 3;

    const int t = threadIdx.x;
    const int lane = t & 63;
    const int w = t >> 6;          // wave -> query rows w*64 .. w*64+63
    const int quad = lane >> 4;
    const int ln = lane & 15;
    const int rbase = bx * TQB + w * 64;
    const int c0 = by * chunk;
    const int c1 = min(c0 + chunk, M);
    const int nt = (c1 - c0 + BR - 1) / BR;   // block-uniform (9 here)

    // A fragments straight from global: rows rbase + rt*16 + ln,
    // loop-invariant.  zb is 0.5 MB -> L2-resident; one-time cost.
    bf16x8 afr[4][4];
    #pragma unroll
    for (int rt = 0; rt < 4; ++rt)
        #pragma unroll
        for (int ks = 0; ks < 4; ++ks)
            afr[rt][ks] = *(const bf16x8*)
                &zb[(size_t)(rbase + rt * 16 + ln) * D_DIM + ks * 32 + quad * 8];

    float mx[4][4];   // pass1: per-lane subset max, rows rt*16+quad*4+r
    float tr[4][4];   // pass2: per-row thresholds
    if (PASS == 1) {
        #pragma unroll
        for (int rt = 0; rt < 4; ++rt)
            #pragma unroll
            for (int r = 0; r < 4; ++r) mx[rt][r] = -3.0f;
    } else {
        #pragma unroll
        for (int rt = 0; rt < 4; ++rt)
            #pragma unroll
            for (int r = 0; r < 4; ++r)
                tr[rt][r] = T[rbase + rt * 16 + quad * 4 + r];
    }

    // Stage one 64-row tile into LDS half `half`.  Per wave: 4 glds calls,
    // each 4 rows (64 lanes x 16B = 1KB, linear dest).  Source slot is
    // pre-swizzled so LDS row r physical slot p holds logical slot p^(r&15).
    auto stage = [&](int half, int tile) {
        const int s0 = c0 + tile * BR;
        #pragma unroll
        for (int i = 0; i < 4; ++i) {
            const int r = w * 16 + i * 4 + quad;        // lane's source row
            int g = s0 + r; if (g > M - 1) g = M - 1;   // clamp; excluded below
            const int sl = ln ^ (r & 15);               // inverse-swizzled slot
            gld_lds16(&rb[(size_t)g * D_DIM + sl * 8],
                      &Bt[half * (BR * D_DIM) + (w * 16 + i * 4) * D_DIM]);
        }
    };

    stage(0, 0);
    stage(1, nt > 1 ? 1 : 0);

    for (int it = 0; it < nt; ++it) {
        // Wait only for THIS tile's 4 stage loads (tile it+1's 4 stay in
        // flight).  Last iteration has no younger stage group -> drain.
        if (it + 1 < nt) asm volatile("s_waitcnt vmcnt(4)" ::: "memory");
        else             asm volatile("s_waitcnt vmcnt(0)" ::: "memory");
        __builtin_amdgcn_s_barrier();
        asm volatile("" ::: "memory");        // no LDS reads hoisted above
        __builtin_amdgcn_sched_barrier(0);

        const int cur = it & 1;
        const int s0 = c0 + it * BR;
        const unsigned short* Bc = &Bt[cur * (BR * D_DIM)];

        // 4 col-tiles of 16 refs; acc[4] (16 VGPR) live per ct only.
        #pragma unroll
        for (int ct = 0; ct < 4; ++ct) {
            f32x4 acc[4];
            #pragma unroll
            for (int rt = 0; rt < 4; ++rt) acc[rt] = (f32x4){0.f,0.f,0.f,0.f};

            __builtin_amdgcn_s_setprio(1);
            #pragma unroll
            for (int ks = 0; ks < 4; ++ks) {
                const int r = ct * 16 + ln;            // r & 15 == ln
                bf16x8 bfr = *(const bf16x8*)
                    &Bc[r * D_DIM + ((ks * 4 + quad) ^ ln) * 8];  // swizzled
                #pragma unroll
                for (int rt = 0; rt < 4; ++rt)
                    acc[rt] = __builtin_amdgcn_mfma_f32_16x16x32_bf16(
                        afr[rt][ks], bfr, acc[rt], 0, 0, 0);
            }
            __builtin_amdgcn_s_setprio(0);

            // Epilogue for this col-tile.  Lane's column g uniform over rt/r.
            const int g = s0 + ct * 16 + ln;
            if (g < c1) {                      // chunk mask: subsets partition
                if (PASS == 1) {
                    #pragma unroll
                    for (int rt = 0; rt < 4; ++rt)
                        #pragma unroll
                        for (int r = 0; r < 4; ++r)
                            mx[rt][r] = fmaxf(mx[rt][r], acc[rt][r]);
                } else {
                    #pragma unroll
                    for (int rt = 0; rt < 4; ++rt)
                        #pragma unroll
                        for (int r = 0; r < 4; ++r) {
                            float v = acc[rt][r];
                            if (v >= tr[rt][r]) {   // rare
                                int row = rbase + rt * 16 + quad * 4 + r;
                                int slot = atomicAdd(&cnt[row], 1);
                                if (slot < CAP) surv[(size_t)row * CAP + slot] = v;
                            }
                        }
                }
            }
        }

        __builtin_amdgcn_sched_barrier(0);
        asm volatile("" ::: "memory");        // no LDS reads sunk below
        __builtin_amdgcn_s_barrier();          // all waves done reading buf[cur]
        if (it + 2 < nt) stage(cur, it + 2);   // refill the buffer just read
    }

    if (PASS == 1) {
        #pragma unroll
        for (int rt = 0; rt < 4; ++rt)
            #pragma unroll
            for (int r = 0; r < 4; ++r) {
                int row = rbase + rt * 16 + quad * 4 + r;
                maxes[(size_t)row * NSUB + by * 16 + ln] = mx[rt][r];
            }
    }
}

// Per-lane sorted top-(KK) slots, then kk+1 global max-extractions with
// static-shift pop (rule #20: no dynamic register indexing).
__device__ __forceinline__ float kth_largest_64(float* s, int kk, int t) {
    float cur = -3.0f;
    for (int it = 0; it <= kk; ++it) {
        float m = s[0];
        #pragma unroll
        for (int off = 32; off > 0; off >>= 1) m = fmaxf(m, __shfl_xor(m, off));
        cur = m;
        unsigned long long b = __ballot(s[0] == m);
        bool owner = ((int)(__ffsll(b) - 1) == t);
        #pragma unroll
        for (int j = 0; j < KK - 1; ++j) s[j] = owner ? s[j + 1] : s[j];
        if (owner) s[KK - 1] = -3.0f;
    }
    return cur;
}

__global__ __launch_bounds__(64) void knn_threshold(
    const float* __restrict__ maxes, const int* __restrict__ kp,
    float* __restrict__ T, int* __restrict__ cnt)
{
    const int row = blockIdx.x;
    const int t = threadIdx.x;
    float s[KK];
    #pragma unroll
    for (int j = 0; j < KK; ++j) s[j] = -3.0f;
    #pragma unroll
    for (int i = 0; i < NSUB / 64; ++i) {     // 24 coalesced loads
        float v = maxes[(size_t)row * NSUB + t + 64 * i];
        #pragma unroll
        for (int j = 0; j < KK; ++j) {        // descending sorted insert
            float hi = fmaxf(s[j], v), lo = fminf(s[j], v);
            s[j] = hi; v = lo;
        }
    }
    const int kk = *kp;   // 10
    float cur = kth_largest_64(s, kk, t);
    if (t == 0) { T[row] = cur; cnt[row] = 0; }
}

__global__ __launch_bounds__(64) void knn_final(
    const float* __restrict__ surv, const int* __restrict__ cnt,
    const int* __restrict__ kp, float* __restrict__ out)
{
    const int row = blockIdx.x;
    const int t = threadIdx.x;
    int c = cnt[row]; if (c > CAP) c = CAP;
    float s[KK];
    #pragma unroll
    for (int j = 0; j < KK; ++j) s[j] = -3.0f;
    #pragma unroll
    for (int i = 0; i < CAP / 64; ++i) {      // 4 coalesced loads
        int idx = t + 64 * i;
        float v = (idx < c) ? surv[(size_t)row * CAP + idx] : -3.0f;
        #pragma unroll
        for (int j = 0; j < KK; ++j) {
            float hi = fmaxf(s[j], v), lo = fminf(s[j], v);
            s[j] = hi; v = lo;
        }
    }
    const int kk = *kp;
    float cur = kth_largest_64(s, kk, t);
    if (t == 0) out[row] = sqrtf(fmaxf(2.0f - 2.0f * cur, 1e-12f));
}

extern "C" void kernel_launch(void* const* d_in, const int* in_sizes, int n_in,
                              void* d_out, int out_size, void* d_ws, size_t ws_size,
                              hipStream_t stream) {
    const float* z   = (const float*)d_in[0];
    const float* ref = (const float*)d_in[1];
    const int*   kp  = (const int*)d_in[2];
    float* out = (float*)d_out;

    const int N = in_sizes[0] / D_DIM;   // 2048
    const int M = in_sizes[1] / D_DIM;   // 50000

    unsigned short* zbuf = (unsigned short*)d_ws;             // N*128 bf16
    unsigned short* rbuf = zbuf + (size_t)N * D_DIM;          // M*128 bf16
    float* maxes = (float*)(rbuf + (size_t)M * D_DIM);        // N*NSUB f32 (12.6MB)
    float* T     = maxes + (size_t)N * NSUB;                  // N f32
    int*   cnt   = (int*)(T + N);                             // N i32
    float* surv  = (float*)(cnt + N);                         // N*CAP f32 (2MB)

    normalize_bf16<<<(N + M + 3) / 4, 256, 0, stream>>>(z, ref, zbuf, rbuf, N, M);

    const int chunk = (M + NCH - 1) / NCH;    // 521
    dim3 grid(N / TQB, NCH);                  // 8 x 96 = 768 blocks, 3/CU

    knn_pass<1><<<grid, 256, 0, stream>>>(zbuf, rbuf, maxes, nullptr,
                                          nullptr, nullptr, N, M, chunk);
    knn_threshold<<<N, 64, 0, stream>>>(maxes, kp, T, cnt);
    knn_pass<2><<<grid, 256, 0, stream>>>(zbuf, rbuf, nullptr, T,
                                          cnt, surv, N, M, chunk);
    knn_final<<<N, 64, 0, stream>>>(surv, cnt, kp, out);
}

// Round 8
// 165.303 us; speedup vs baseline: 1.2817x; 1.1323x over previous
//
#include <hip/hip_runtime.h>

// KNN k-th smallest distance, two-pass threshold-filter MFMA version.
// dist = sqrt(2 - 2*dot(zn,rn)); sorted(dist)[k] == (k+1)-th LARGEST dot.
//  1) normalize_bf16: fused z+ref rows -> L2-normalized bf16
//  2) knn_pass<1>:  MFMA dots, per-(row,residue) subset MAX (in-register)
//  3) knn_threshold: per row, exact 11th-largest of 1024 subset maxes -> T
//  4) knn_pass<2>:  MFMA dots again, keep v >= T[row] via atomic append
//  5) knn_final: exact 11th-largest of survivors -> dist
//
// Round-8: verified 8-wave/256-query attention shape (this op IS attention's
// QK^T+rowmax).  Ledger: r3 = 587 TF == m233's 2-phase plateau (607); all
// intra-plateau knobs null (r0/r1/r3/r5); 64-rows/wave always worse
// (r2/r6/r7).  Catalog exit: 256-tile + 8-wave regime (m230: 682 TF at
// 2-phase; m214 attn: ts_qo=256, ts_kv=64, 8 waves, 32 q-rows/wave).
//  - swapped-operand mfma_32x32x16(K,Q): C col = q-row (lane&31) [m74/m101
//    verified layout], C rows = refs -> per-lane threshold (pass 2) is ONE
//    register; subset max is in-lane fmax over unrolled reg indices.
//  - wave = 32 q-rows x all 64 refs/tile: 16 MFMA(32x32) + 16 ds_read_b128
//    per iter; only 2 acc chains (2 x f32x16).
//  - staging machinery = r3 known-good: gld_lds w16, 32KB double-buffer,
//    counted vmcnt(2) (2 stage calls/wave), XOR slot swizzle via
//    pre-swizzled global source.  One barrier pair per iter.
//  - subsets: (q-row, residue r): mx[16] accumulated in-lane over the chunk;
//    halves merged with one shfl_xor(32) at kernel end -> NSUB = 64x16 =
//    1024 (threshold kernel unchanged from r5).
//  - grid 8 x 64 = 512 blocks = 2/CU (16 waves/CU); 512%8==0 bijective XCD
//    swizzle; 8 chunks/XCD = 1.6MB L2-fit.  No launch-bounds min (r4 lesson).
//
// Accuracy: bf16 rounding perturbs each dot by ~3.5e-4; k-th order statistic
// is 1-Lipschitz in that perturbation -> << 2.39e-2 threshold.  Threshold
// bound: subsets (chunk, residue-pair) PARTITION each row's refs (masked
// tails excluded); a subset max > v11 implies the subset holds a top-10 dot
// -> at most 10 such subsets -> T (11th-largest subset max) <= v11, so all
// top-11 dots survive the v >= T filter.

#define D_DIM 128
#define TQB 256        // queries per block (8 waves x 32 rows)
#define BR 64          // refs per block iteration
#define NCH 64         // ref chunks; grid 8*64=512 blocks = 2/CU; 512%8==0
#define NSUB (NCH * 16) // subsets per row = 1024
#define KK 11          // selection slots (k=10 -> 11th largest)
#define CAP 256        // survivor capacity per row

typedef __bf16 bf16_t;
typedef bf16_t bf16x8 __attribute__((ext_vector_type(8)));
typedef float f32x16 __attribute__((ext_vector_type(16)));

__device__ __forceinline__ unsigned short f2bf(float f) {
    unsigned u = __float_as_uint(f);
    return (unsigned short)((u + 0x7fffu + ((u >> 16) & 1u)) >> 16);  // RNE
}

__global__ __launch_bounds__(256) void normalize_bf16(
    const float* __restrict__ z, const float* __restrict__ ref,
    unsigned short* __restrict__ zb, unsigned short* __restrict__ rb,
    int N, int M)
{
    const int w = threadIdx.x >> 6;
    const int l = threadIdx.x & 63;
    const int row = blockIdx.x * 4 + w;
    if (row >= N + M) return;
    const float* in; unsigned short* out; int r;
    if (row < N) { in = z;   out = zb; r = row; }
    else         { in = ref; out = rb; r = row - N; }
    const float2 v = ((const float2*)in)[(size_t)r * 64 + l];
    float ss = v.x * v.x + v.y * v.y;
    #pragma unroll
    for (int off = 32; off > 0; off >>= 1) ss += __shfl_xor(ss, off);
    const float inv = rsqrtf(ss);
    ushort2 o; o.x = f2bf(v.x * inv); o.y = f2bf(v.y * inv);
    ((ushort2*)out)[(size_t)r * 64 + l] = o;
}

// async global->LDS, 16B per lane; LDS dest is wave-uniform base + lane*16.
__device__ __forceinline__ void gld_lds16(const unsigned short* g,
                                          unsigned short* l) {
    __builtin_amdgcn_global_load_lds(
        (__attribute__((address_space(1))) void*)g,
        (__attribute__((address_space(3))) void*)l, 16, 0, 0);
}

// PASS==1: write subset maxes.  PASS==2: filter vs T, append survivors.
template <int PASS>
__global__ __launch_bounds__(512) void knn_pass(
    const unsigned short* __restrict__ zb, const unsigned short* __restrict__ rb,
    float* __restrict__ maxes, const float* __restrict__ T,
    int* __restrict__ cnt, float* __restrict__ surv,
    int N, int M, int chunk)
{
    // Double-buffered K(ref) tile: 2 x 64 rows x 128 bf16, 32 KiB.  No pad;
    // bank spread via XOR slot swizzle (0 conflicts measured, r1-r5).
    __shared__ __align__(16) unsigned short Bt[2 * BR * D_DIM];

    // T1 XCD swizzle: XCD k owns ref-chunks [8k,8k+8) exclusively (1.6MB,
    // L2-fit); all 8 q-blocks of a chunk land on the same XCD.
    const int nwg = 8 * NCH;                              // 512, %8 == 0
    const int bid = (int)blockIdx.x + 8 * (int)blockIdx.y;
    const int swz = (bid & 7) * (nwg >> 3) + (bid >> 3);
    const int bx = swz & 7;
    const int by = swz >> 3;

    const int t = threadIdx.x;
    const int lane = t & 63;
    const int w = t >> 6;          // wave 0..7 -> q-rows w*32 .. w*32+31
    const int quad = lane >> 4;
    const int ln = lane & 15;
    const int l31 = lane & 31;
    const int hi = lane >> 5;      // ref-row +4 offset class
    const int rbase = bx * TQB + w * 32;
    const int row = rbase + l31;   // this lane's q-row (all its dots)
    const int c0 = by * chunk;
    const int c1 = min(c0 + chunk, M);
    const int clen = c1 - c0;
    const int nt = (clen + BR - 1) / BR;   // block-uniform (12-13 here)

    // Q fragments (B operand), loop-invariant, from L2-resident zb.
    // B layout 32x32x16: col = lane&31 (q), k = ks*16 + (lane>>5)*8 + e.
    bf16x8 qfr[8];
    #pragma unroll
    for (int ks = 0; ks < 8; ++ks)
        qfr[ks] = *(const bf16x8*)
            &zb[(size_t)row * D_DIM + ks * 16 + hi * 8];

    float mx[16];     // pass1: subset max per reg-residue (in-lane)
    float tr = 0.f;   // pass2: this lane's row threshold (ONE register)
    if (PASS == 1) {
        #pragma unroll
        for (int r = 0; r < 16; ++r) mx[r] = -3.0f;
    } else {
        tr = T[row];
    }

    // Stage one 64-ref tile into LDS half `half`.  Per wave: 2 glds calls,
    // each 4 rows (64 lanes x 16B = 1KB, linear dest).  Source slot is
    // pre-swizzled so LDS row r physical slot p holds logical slot p^(r&15).
    auto stage = [&](int half, int tile) {
        const int s0 = c0 + tile * BR;
        #pragma unroll
        for (int i = 0; i < 2; ++i) {
            const int r = w * 8 + i * 4 + quad;         // lane's source row
            int g = s0 + r; if (g > M - 1) g = M - 1;   // clamp; masked below
            const int sl = ln ^ (r & 15);               // inverse-swizzled slot
            gld_lds16(&rb[(size_t)g * D_DIM + sl * 8],
                      &Bt[half * (BR * D_DIM) + (w * 8 + i * 4) * D_DIM]);
        }
    };

    stage(0, 0);
    stage(1, nt > 1 ? 1 : 0);

    for (int it = 0; it < nt; ++it) {
        // Wait for THIS tile's 2 stage loads (tile it+1's 2 stay in flight).
        if (it + 1 < nt) asm volatile("s_waitcnt vmcnt(2)" ::: "memory");
        else             asm volatile("s_waitcnt vmcnt(0)" ::: "memory");
        __builtin_amdgcn_s_barrier();
        asm volatile("" ::: "memory");        // no LDS reads hoisted above
        __builtin_amdgcn_sched_barrier(0);

        const int cur = it & 1;
        const unsigned short* Bc = &Bt[cur * (BR * D_DIM)];

        f32x16 acc0 = {0,0,0,0,0,0,0,0,0,0,0,0,0,0,0,0};
        f32x16 acc1 = {0,0,0,0,0,0,0,0,0,0,0,0,0,0,0,0};

        __builtin_amdgcn_s_setprio(1);
        #pragma unroll
        for (int ks = 0; ks < 8; ++ks) {
            // A (K-refs) layout 32x32x16: row = lane&31, k = ks*16 + hi*8.
            // 16B slot s = ks*2 + hi, physical slot = s ^ (row&15) = s ^ ln.
            const int sl = ((ks * 2 + hi) ^ ln) * 8;
            bf16x8 a0 = *(const bf16x8*)&Bc[(l31)      * D_DIM + sl];
            bf16x8 a1 = *(const bf16x8*)&Bc[(32 + l31) * D_DIM + sl];
            acc0 = __builtin_amdgcn_mfma_f32_32x32x16_bf16(a0, qfr[ks], acc0, 0, 0, 0);
            acc1 = __builtin_amdgcn_mfma_f32_32x32x16_bf16(a1, qfr[ks], acc1, 0, 0, 0);
        }
        __builtin_amdgcn_s_setprio(0);

        // Epilogue.  acc0/acc1 reg r holds dot(q=row, ref = c0 + it*64 +
        // {0,32} + crow) with crow = (r&3) + 8*(r>>2) + 4*hi  [m74/m101].
        const int rem = clen - it * BR;       // valid refs in this tile
        if (rem >= BR) {                      // fast path: all 64 valid
            if (PASS == 1) {
                #pragma unroll
                for (int r = 0; r < 16; ++r)
                    mx[r] = fmaxf(mx[r], fmaxf(acc0[r], acc1[r]));
            } else {
                #pragma unroll
                for (int r = 0; r < 16; ++r) {
                    float v0 = acc0[r], v1 = acc1[r];
                    if (v0 >= tr) {           // rare
                        int slot = atomicAdd(&cnt[row], 1);
                        if (slot < CAP) surv[(size_t)row * CAP + slot] = v0;
                    }
                    if (v1 >= tr) {
                        int slot = atomicAdd(&cnt[row], 1);
                        if (slot < CAP) surv[(size_t)row * CAP + slot] = v1;
                    }
                }
            }
        } else {                              // tail tile: mask by ref row
            #pragma unroll
            for (int r = 0; r < 16; ++r) {
                const int crow = (r & 3) + 8 * (r >> 2) + 4 * hi;
                const bool ok0 = crow < rem;
                const bool ok1 = 32 + crow < rem;
                if (PASS == 1) {
                    if (ok0) mx[r] = fmaxf(mx[r], acc0[r]);
                    if (ok1) mx[r] = fmaxf(mx[r], acc1[r]);
                } else {
                    float v0 = acc0[r], v1 = acc1[r];
                    if (ok0 && v0 >= tr) {
                        int slot = atomicAdd(&cnt[row], 1);
                        if (slot < CAP) surv[(size_t)row * CAP + slot] = v0;
                    }
                    if (ok1 && v1 >= tr) {
                        int slot = atomicAdd(&cnt[row], 1);
                        if (slot < CAP) surv[(size_t)row * CAP + slot] = v1;
                    }
                }
            }
        }

        __builtin_amdgcn_sched_barrier(0);
        asm volatile("" ::: "memory");        // no LDS reads sunk below
        __builtin_amdgcn_s_barrier();          // all waves done reading buf[cur]
        if (it + 2 < nt) stage(cur, it + 2);   // refill the buffer just read
    }

    if (PASS == 1) {
        // Merge hi/lo halves (lane l <-> l+32 share the same q-row) and
        // store 16 subset maxes per row for this chunk.
        #pragma unroll
        for (int r = 0; r < 16; ++r) {
            float m2 = fmaxf(mx[r], __shfl_xor(mx[r], 32));
            if (hi == 0)
                maxes[(size_t)row * NSUB + by * 16 + r] = m2;
        }
    }
}

// Per-lane sorted top-(KK) slots, then kk+1 global max-extractions with
// static-shift pop (rule #20: no dynamic register indexing).
__device__ __forceinline__ float kth_largest_64(float* s, int kk, int t) {
    float cur = -3.0f;
    for (int it = 0; it <= kk; ++it) {
        float m = s[0];
        #pragma unroll
        for (int off = 32; off > 0; off >>= 1) m = fmaxf(m, __shfl_xor(m, off));
        cur = m;
        unsigned long long b = __ballot(s[0] == m);
        bool owner = ((int)(__ffsll(b) - 1) == t);
        #pragma unroll
        for (int j = 0; j < KK - 1; ++j) s[j] = owner ? s[j + 1] : s[j];
        if (owner) s[KK - 1] = -3.0f;
    }
    return cur;
}

__global__ __launch_bounds__(64) void knn_threshold(
    const float* __restrict__ maxes, const int* __restrict__ kp,
    float* __restrict__ T, int* __restrict__ cnt)
{
    const int row = blockIdx.x;
    const int t = threadIdx.x;
    float s[KK];
    #pragma unroll
    for (int j = 0; j < KK; ++j) s[j] = -3.0f;
    #pragma unroll
    for (int i = 0; i < NSUB / 64; ++i) {     // 16 coalesced loads
        float v = maxes[(size_t)row * NSUB + t + 64 * i];
        #pragma unroll
        for (int j = 0; j < KK; ++j) {        // descending sorted insert
            float hi = fmaxf(s[j], v), lo = fminf(s[j], v);
            s[j] = hi; v = lo;
        }
    }
    const int kk = *kp;   // 10
    float cur = kth_largest_64(s, kk, t);
    if (t == 0) { T[row] = cur; cnt[row] = 0; }
}

__global__ __launch_bounds__(64) void knn_final(
    const float* __restrict__ surv, const int* __restrict__ cnt,
    const int* __restrict__ kp, float* __restrict__ out)
{
    const int row = blockIdx.x;
    const int t = threadIdx.x;
    int c = cnt[row]; if (c > CAP) c = CAP;
    float s[KK];
    #pragma unroll
    for (int j = 0; j < KK; ++j) s[j] = -3.0f;
    #pragma unroll
    for (int i = 0; i < CAP / 64; ++i) {      // 4 coalesced loads
        int idx = t + 64 * i;
        float v = (idx < c) ? surv[(size_t)row * CAP + idx] : -3.0f;
        #pragma unroll
        for (int j = 0; j < KK; ++j) {
            float hi = fmaxf(s[j], v), lo = fminf(s[j], v);
            s[j] = hi; v = lo;
        }
    }
    const int kk = *kp;
    float cur = kth_largest_64(s, kk, t);
    if (t == 0) out[row] = sqrtf(fmaxf(2.0f - 2.0f * cur, 1e-12f));
}

extern "C" void kernel_launch(void* const* d_in, const int* in_sizes, int n_in,
                              void* d_out, int out_size, void* d_ws, size_t ws_size,
                              hipStream_t stream) {
    const float* z   = (const float*)d_in[0];
    const float* ref = (const float*)d_in[1];
    const int*   kp  = (const int*)d_in[2];
    float* out = (float*)d_out;

    const int N = in_sizes[0] / D_DIM;   // 2048
    const int M = in_sizes[1] / D_DIM;   // 50000

    unsigned short* zbuf = (unsigned short*)d_ws;             // N*128 bf16
    unsigned short* rbuf = zbuf + (size_t)N * D_DIM;          // M*128 bf16
    float* maxes = (float*)(rbuf + (size_t)M * D_DIM);        // N*NSUB f32 (8MB)
    float* T     = maxes + (size_t)N * NSUB;                  // N f32
    int*   cnt   = (int*)(T + N);                             // N i32
    float* surv  = (float*)(cnt + N);                         // N*CAP f32 (2MB)

    normalize_bf16<<<(N + M + 3) / 4, 256, 0, stream>>>(z, ref, zbuf, rbuf, N, M);

    const int chunk = (M + NCH - 1) / NCH;    // 782
    dim3 grid(N / TQB, NCH);                  // 8 x 64 = 512 blocks, 2/CU

    knn_pass<1><<<grid, 512, 0, stream>>>(zbuf, rbuf, maxes, nullptr,
                                          nullptr, nullptr, N, M, chunk);
    knn_threshold<<<N, 64, 0, stream>>>(maxes, kp, T, cnt);
    knn_pass<2><<<grid, 512, 0, stream>>>(zbuf, rbuf, nullptr, T,
                                          cnt, surv, N, M, chunk);
    knn_final<<<N, 64, 0, stream>>>(surv, cnt, kp, out);
}